// Round 14
// baseline (336.522 us; speedup 1.0000x reference)
//
#include <hip/hip_runtime.h>
#include <hip/hip_bf16.h>
#include <math.h>

#define NBATCH 8
#define HWP 4096
#define NTOK 32768
#define NTOKH 16896   // packed half-plane tokens: 8 * 33 * 64
#define CIN 128
#define HID 256
#define MLPH 2048
#define SLOTF 8388608L   // floats per 32MB slot

typedef unsigned short u16;
typedef __attribute__((ext_vector_type(8))) short bf16x8;
typedef __attribute__((ext_vector_type(4))) float f32x4;
typedef __attribute__((ext_vector_type(8))) unsigned short ushort8_t;
typedef __attribute__((ext_vector_type(2))) unsigned long long u64x2;

__device__ __forceinline__ float bf2f(u16 v) { return __uint_as_float(((unsigned)v) << 16); }
__device__ __forceinline__ u16 f2bf(float f) {
    unsigned u = __float_as_uint(f);
    u = u + 0x7fffu + ((u >> 16) & 1u);
    return (u16)(u >> 16);
}
__device__ __forceinline__ u16 bits2bf(unsigned u) {
    u = u + 0x7fffu + ((u >> 16) & 1u);
    return (u16)(u >> 16);
}
// pack 2 fp32 -> u32 of 2 bf16 (hardware cvt_pk)
__device__ __forceinline__ unsigned pk_bf16(float lo, float hi) {
    unsigned r;
    asm("v_cvt_pk_bf16_f32 %0, %1, %2" : "=v"(r) : "v"(lo), "v"(hi));
    return r;
}
__device__ __forceinline__ float sshrink(float v) {
    return v > 0.01f ? v - 0.01f : (v < -0.01f ? v + 0.01f : 0.f);
}
// hardware-native fast gelu
__device__ __forceinline__ float fast_gelu(float v) {
    float z = v * fmaf(0.0713548162726f, v * v, 1.59576912161f);
    float t = __builtin_amdgcn_exp2f(z * -1.44269504088896f);
    return v * __builtin_amdgcn_rcpf(1.f + t);
}

// ---------------- LN1: x (B,128,4096) -> xnb bf16 (B*4096,128) + xb bf16 (B*4096,128) ----------------
__global__ __launch_bounds__(256) void ln1_kernel(const float* __restrict__ x,
    const float* __restrict__ g, const float* __restrict__ be,
    u16* __restrict__ xnb, u16* __restrict__ xb)
{
    __shared__ float xt[CIN][65];
    __shared__ float mu_s[64], rs_s[64];
    int bid = blockIdx.x;
    int b = bid >> 6;
    int t0 = (bid & 63) << 6;
    int tid = threadIdx.x;
    for (int it = 0; it < 32; ++it) {
        int idx = (it << 8) + tid;
        int c = idx >> 6, t = idx & 63;
        xt[c][t] = x[(long)(b * CIN + c) * HWP + t0 + t];
    }
    __syncthreads();
    int tt = tid >> 2, p = tid & 3;
    float s = 0.f, ss = 0.f;
    #pragma unroll
    for (int i = 0; i < 32; ++i) {
        float v = xt[p * 32 + i][tt];
        s += v; ss += v * v;
    }
    s += __shfl_xor(s, 1); ss += __shfl_xor(ss, 1);
    s += __shfl_xor(s, 2); ss += __shfl_xor(ss, 2);
    if (p == 0) {
        float mu = s * (1.f / CIN);
        float var = ss * (1.f / CIN) - mu * mu;
        mu_s[tt] = mu;
        rs_s[tt] = rsqrtf(var + 1e-5f);
    }
    __syncthreads();
    #pragma unroll
    for (int it = 0; it < 16; ++it) {
        int idx = (it << 8) + tid;
        int t = idx >> 6, c2 = (idx & 63) << 1;
        float v0 = (xt[c2][t] - mu_s[t]) * rs_s[t] * g[c2] + be[c2];
        float v1 = (xt[c2 + 1][t] - mu_s[t]) * rs_s[t] * g[c2 + 1] + be[c2 + 1];
        *(unsigned*)&xnb[((long)b * HWP + t0 + t) * CIN + c2] = pk_bf16(v0, v1);
    }
    #pragma unroll
    for (int it = 0; it < 8; ++it) {
        int idx = (it << 8) + tid;
        int t = idx >> 5, c4 = (idx & 31) << 2;
        uint2 pk;
        pk.x = pk_bf16(xt[c4 + 0][t], xt[c4 + 1][t]);
        pk.y = pk_bf16(xt[c4 + 2][t], xt[c4 + 3][t]);
        *(uint2*)&xb[((long)b * HWP + t0 + t) * CIN + c4] = pk;
    }
}

// ---------------- merged static setup: twiddle tables + all weight conversions ----------------
__device__ __forceinline__ void wcvt_body(const float* __restrict__ w, int K,
    u16* __restrict__ out, int idx)
{
    int k = idx >> 8, o = idx & 255;
    float w0 = w[k * 256 + o];
    float w1v = w[K * 256 + k * 256 + o];
    long K2 = 2L * K;
    out[(long)o * K2 + k] = f2bf(w0);
    out[(long)o * K2 + K + k] = f2bf(-w1v);
    out[(long)(256 + o) * K2 + k] = f2bf(w1v);
    out[(long)(256 + o) * K2 + K + k] = f2bf(w0);
}
__device__ __forceinline__ void f2bf_body(const float* __restrict__ in,
    u16* __restrict__ out, int i)
{
    float4 v = *(const float4*)&in[i];
    ushort4 o;
    o.x = f2bf(v.x); o.y = f2bf(v.y); o.z = f2bf(v.z); o.w = f2bf(v.w);
    *(ushort4*)&out[i] = o;
}
__global__ __launch_bounds__(256) void setup_kernel(
    const float* __restrict__ w1, const float* __restrict__ w3,
    const float* __restrict__ w2, const float* __restrict__ fc1w,
    const float* __restrict__ fc2w, const float* __restrict__ pw,
    u16* __restrict__ TWB, u16* __restrict__ W1c, u16* __restrict__ W3c,
    u16* __restrict__ W2c, u16* __restrict__ WB1, u16* __restrict__ WB2,
    u16* __restrict__ PWB)
{
    int bid = blockIdx.x, tid = threadIdx.x;
    if (bid < 64) {
        int idx = bid * 256 + tid;            // n*128 + kcol
        int n = idx >> 7, kcol = idx & 127;
        int j = kcol & 63, p = kcol >> 6;
        int np = n & 63, q = n >> 6;
        float th = 6.283185307179586f * (float)((j * np) & 63) / 64.f;
        float sv, cv;
        sincosf(th, &sv, &cv);
        float fw = (q == 0) ? (p == 0 ? cv : sv) : (p == 0 ? -sv : cv);
        float iv = (q == 0) ? (p == 0 ? cv : -sv) : (p == 0 ? sv : cv);
        fw *= 0.125f; iv *= 0.125f;
        u16 fh = f2bf(fw), ih = f2bf(iv);
        TWB[idx] = fh;
        TWB[16384 + idx] = f2bf(fw - bf2f(fh));
        TWB[32768 + idx] = ih;
        TWB[49152 + idx] = f2bf(iv - bf2f(ih));
    } else if (bid < 192) {
        wcvt_body(w1, 128, W1c, (bid - 64) * 256 + tid);
    } else if (bid < 448) {
        wcvt_body(w3, 256, W3c, (bid - 192) * 256 + tid);
    } else if (bid < 704) {
        wcvt_body(w2, 256, W2c, (bid - 448) * 256 + tid);
    } else if (bid < 1216) {
        f2bf_body(fc1w, WB1, ((bid - 704) * 256 + tid) * 4);
    } else if (bid < 1728) {
        f2bf_body(fc2w, WB2, ((bid - 1216) * 256 + tid) * 4);
    } else {
        f2bf_body(pw, PWB, ((bid - 1728) * 256 + tid) * 4);
    }
}

// ---------------- MFMA 64-pt DFT along one axis ----------------
// INMODE 0: fp32 in, c-contig runs, real (K=64)
// INMODE 1: bf16 in, c-contig runs, cplx (K=128)
// INMODE 2: fp32 in, j-contig rows, real (K=64)
// INMODE 3: bf16 in, c-contig runs, real (K=64)
template<int INMODE, int REALOUT, int NT, int USELO>
__global__ __launch_bounds__(256) void dftm_kernel(
    const void* __restrict__ inp, const u16* __restrict__ tw,
    void* __restrict__ outp, const float* __restrict__ addend,
    int nch, long IB, long IK, long IC, long JS, long PS,
    long OB, long OK, long OC, long KS, long PS2, int kmax)
{
    constexpr int K = (INMODE == 1) ? 128 : 64;
    constexpr int AST = (K == 128) ? 136 : 72;
    constexpr int MFR = REALOUT ? 2 : 4;
    __shared__ __align__(16) u16 smem[128 * 136];
    int tid = threadIdx.x;
    int lane = tid & 63;
    int bid = blockIdx.x;
    int b = bid / (64 * nch);
    int rem = bid % (64 * nch);
    int keep = rem / nch;
    int ch = rem % nch;
    long ibase = b * IB + keep * IK + ch * IC;
    long obase = b * OB + keep * OK + ch * OC;

    if (INMODE == 0) {
        const float* inF = (const float*)inp;
        #pragma unroll
        for (int it = 0; it < 8; ++it) {
            int idx = (it << 8) + tid;
            int j = idx >> 5, c4 = (idx & 31) << 2;
            u64x2 v = *(const u64x2*)(inF + ibase + (long)j * JS + c4);
            #pragma unroll
            for (int i = 0; i < 4; ++i) {
                int vv = (i + lane) & 3;
                unsigned long long q = (vv & 2) ? v.y : v.x;
                unsigned fb = (unsigned)(q >> ((vv & 1) << 5));
                smem[(c4 + vv) * AST + j] = bits2bf(fb);
            }
        }
    } else if (INMODE == 1) {
        const u16* inU = (const u16*)inp;
        #pragma unroll
        for (int it = 0; it < 8; ++it) {
            int idx = (it << 8) + tid;
            int run = idx >> 4, c8 = (idx & 15) << 3;
            int j = run >> 1, p = run & 1;
            u64x2 v = *(const u64x2*)(inU + ibase + (long)j * JS + (long)p * PS + c8);
            int col = p * 64 + j;
            #pragma unroll
            for (int i = 0; i < 8; ++i) {
                int vv = (i + lane) & 7;
                unsigned long long q = (vv & 4) ? v.y : v.x;
                u16 val = (u16)(q >> ((vv & 3) << 4));
                smem[(c8 + vv) * AST + col] = val;
            }
        }
    } else if (INMODE == 3) {
        const u16* inU = (const u16*)inp;
        #pragma unroll
        for (int it = 0; it < 4; ++it) {
            int idx = (it << 8) + tid;
            int j = idx >> 4, c8 = (idx & 15) << 3;
            u64x2 v = *(const u64x2*)(inU + ibase + (long)j * JS + c8);
            #pragma unroll
            for (int i = 0; i < 8; ++i) {
                int vv = (i + lane) & 7;
                unsigned long long q = (vv & 4) ? v.y : v.x;
                u16 val = (u16)(q >> ((vv & 3) << 4));
                smem[(c8 + vv) * AST + j] = val;
            }
        }
    } else {
        const float* inF = (const float*)inp;
        #pragma unroll
        for (int it = 0; it < 8; ++it) {
            int idx = (it << 8) + tid;
            int row = idx >> 4, j4 = (idx & 15) << 2;
            u64x2 v = *(const u64x2*)(inF + ibase + (long)row * JS + j4);
            ushort4 o;
            o.x = bits2bf((unsigned)v.x);
            o.y = bits2bf((unsigned)(v.x >> 32));
            o.z = bits2bf((unsigned)v.y);
            o.w = bits2bf((unsigned)(v.y >> 32));
            *(ushort4*)&smem[row * AST + j4] = o;
        }
    }
    __syncthreads();

    int w = tid >> 6;
    int ln15 = lane & 15, kg = lane >> 4;
    int wrow = REALOUT ? (w << 5) : ((w >> 1) << 6);
    int wcol = REALOUT ? 0 : ((w & 1) << 6);
    f32x4 acc[MFR][NT] = {};
    #pragma unroll
    for (int kk = 0; kk < K / 32; ++kk) {
        bf16x8 av[MFR];
        #pragma unroll
        for (int m = 0; m < MFR; ++m)
            av[m] = *(const bf16x8*)&smem[(wrow + m * 16 + ln15) * AST + kk * 32 + kg * 8];
        #pragma unroll
        for (int n = 0; n < NT; ++n) {
            const u16* tb = tw + (wcol + n * 16 + ln15) * 128 + kk * 32 + kg * 8;
            bf16x8 bh = *(const bf16x8*)tb;
            #pragma unroll
            for (int m = 0; m < MFR; ++m)
                acc[m][n] = __builtin_amdgcn_mfma_f32_16x16x32_bf16(av[m], bh, acc[m][n], 0, 0, 0);
            if (USELO) {
                bf16x8 bl = *(const bf16x8*)(tb + 16384);
                #pragma unroll
                for (int m = 0; m < MFR; ++m)
                    acc[m][n] = __builtin_amdgcn_mfma_f32_16x16x32_bf16(av[m], bl, acc[m][n], 0, 0, 0);
            }
        }
    }
    __syncthreads();

    if (REALOUT == 0) {
        #pragma unroll
        for (int m = 0; m < MFR; ++m)
            #pragma unroll
            for (int n = 0; n < NT; ++n) {
                int base = (wcol + n * 16 + ln15) * 136 + wrow + m * 16 + kg * 4;
                uint2 pk;
                pk.x = pk_bf16(acc[m][n][0], acc[m][n][1]);
                pk.y = pk_bf16(acc[m][n][2], acc[m][n][3]);
                *(uint2*)&smem[base] = pk;
            }
        __syncthreads();
        u16* outU = (u16*)outp;
        #pragma unroll
        for (int it = 0; it < 8; ++it) {
            int idx = (it << 8) + tid;
            int n = idx >> 4, c8 = (idx & 15) << 3;
            int k = n & 63, p = n >> 6;
            if (k <= kmax)
                *(ushort8_t*)&outU[obase + (long)k * KS + (long)p * PS2 + c8] =
                    *(const ushort8_t*)&smem[n * 136 + c8];
        }
    } else {
        float* ef = (float*)smem;  // [64][132]
        #pragma unroll
        for (int m = 0; m < MFR; ++m)
            #pragma unroll
            for (int n = 0; n < NT; ++n) {
                float4 vv = make_float4(acc[m][n][0], acc[m][n][1], acc[m][n][2], acc[m][n][3]);
                *(float4*)&ef[(n * 16 + ln15) * 132 + wrow + m * 16 + kg * 4] = vv;
            }
        __syncthreads();
        float* outF = (float*)outp;
        #pragma unroll
        for (int it = 0; it < 8; ++it) {
            int idx = (it << 8) + tid;
            int k = idx >> 5, c4 = (idx & 31) << 2;
            long a = obase + (long)k * KS + c4;
            float4 v = *(const float4*)&ef[k * 132 + c4];
            float4 rv = *(const float4*)&addend[a];
            v.x += rv.x; v.y += rv.y; v.z += rv.z; v.w += rv.w;
            *(float4*)&outF[a] = v;
        }
    }
}

// ---------------- modulation + channel softmax: half-plane in, full plane out ----------------
__global__ __launch_bounds__(256) void mod_kernel(
    const u16* __restrict__ x1, const u16* __restrict__ p3,
    const float* __restrict__ alpha, u16* __restrict__ a2)
{
    int tid = threadIdx.x;
    int lane = tid & 63;
    int wv = tid >> 6;
    int tp = blockIdx.x * 4 + wv;          // packed token, 0..16895
    int b = tp / 2112;
    int r = tp - b * 2112;
    int kh = r >> 6, kw = r & 63;
    long ibase = (long)tp * 512 + lane * 4;
    ushort4 xr4 = *(const ushort4*)&x1[ibase];
    ushort4 xi4 = *(const ushort4*)&x1[ibase + 256];
    ushort4 pr4 = *(const ushort4*)&p3[ibase];
    ushort4 pi4 = *(const ushort4*)&p3[ibase + 256];
    float4 al4 = *(const float4*)&alpha[lane * 4];
    u16 xru[4] = {xr4.x, xr4.y, xr4.z, xr4.w};
    u16 xiu[4] = {xi4.x, xi4.y, xi4.z, xi4.w};
    u16 pru[4] = {pr4.x, pr4.y, pr4.z, pr4.w};
    u16 piu[4] = {pi4.x, pi4.y, pi4.z, pi4.w};
    float alv[4] = {al4.x, al4.y, al4.z, al4.w};
    float mo[4], oc[4], os[4], sim[4];
    #pragma unroll
    for (int q = 0; q < 4; ++q) {
        float xr = bf2f(xru[q]), xi = bf2f(xiu[q]);
        float pr = bf2f(pru[q]), pi = bf2f(piu[q]);
        float al = alv[q];
        float m = __builtin_amdgcn_sqrtf(xr * xr + xi * xi);
        float mp = __builtin_amdgcn_sqrtf(pr * pr + pi * pi);
        float cx, sx, cp, sp;
        if (m > 0.f) { float rr = __builtin_amdgcn_rcpf(m); cx = xr * rr; sx = xi * rr; }
        else { cx = 1.f; sx = 0.f; }
        if (mp > 0.f) { float rr = __builtin_amdgcn_rcpf(mp); cp = pr * rr; sp = pi * rr; }
        else { cp = 1.f; sp = 0.f; }
        float sc = al * cx + (1.f - al) * cp;
        float ssn = al * sx + (1.f - al) * sp;
        float rn = __builtin_amdgcn_rsqf(sc * sc + ssn * ssn + 1e-8f);
        mo[q] = m;
        oc[q] = sc * rn;
        os[q] = ssn * rn;
        float cross = pr * xr + pi * xi;
        sim[q] = cross * __builtin_amdgcn_rcpf(mp * m + 1e-8f);
    }
    float mv = fmaxf(fmaxf(sim[0], sim[1]), fmaxf(sim[2], sim[3]));
    #pragma unroll
    for (int off = 1; off < 64; off <<= 1) mv = fmaxf(mv, __shfl_xor(mv, off));
    float e[4];
    float sum = 0.f;
    #pragma unroll
    for (int q = 0; q < 4; ++q) {
        e[q] = __builtin_amdgcn_exp2f((sim[q] - mv) * 1.44269504088896f);
        sum += e[q];
    }
    #pragma unroll
    for (int off = 1; off < 64; off <<= 1) sum += __shfl_xor(sum, off);
    float rs = __builtin_amdgcn_rcpf(sum);
    float orf[4], ipf[4], imf[4];
    #pragma unroll
    for (int q = 0; q < 4; ++q) {
        float mag = mo[q] * e[q] * rs;
        orf[q] = fmaxf(mag * oc[q], 0.f);
        ipf[q] = fmaxf(mag * os[q], 0.f);
        imf[q] = fmaxf(-mag * os[q], 0.f);
    }
    uint2 o_r, o_ip, o_im;
    o_r.x = pk_bf16(orf[0], orf[1]);  o_r.y = pk_bf16(orf[2], orf[3]);
    o_ip.x = pk_bf16(ipf[0], ipf[1]); o_ip.y = pk_bf16(ipf[2], ipf[3]);
    o_im.x = pk_bf16(imf[0], imf[1]); o_im.y = pk_bf16(imf[2], imf[3]);
    long pbase = ((long)b * 4096 + kh * 64 + kw) * 512 + lane * 4;
    *(uint2*)&a2[pbase] = o_r;
    *(uint2*)&a2[pbase + 256] = o_ip;
    if (kh >= 1 && kh <= 31) {
        long mbase = ((long)b * 4096 + (64 - kh) * 64 + ((64 - kw) & 63)) * 512 + lane * 4;
        *(uint2*)&a2[mbase] = o_r;
        *(uint2*)&a2[mbase + 256] = o_im;
    }
}

// ---------------- LN2 over 256 channels -> bf16 out ----------------
__global__ __launch_bounds__(256) void ln2_kernel(const float* __restrict__ h,
    const float* __restrict__ g, const float* __restrict__ be, u16* __restrict__ m)
{
    int t = blockIdx.x, c = threadIdx.x;
    float v = h[(long)t * HID + c];
    float s = v, ss = v * v;
    #pragma unroll
    for (int off = 1; off < 64; off <<= 1) { s += __shfl_xor(s, off); ss += __shfl_xor(ss, off); }
    __shared__ float r1[4], r2[4];
    int wid = c >> 6;
    if ((c & 63) == 0) { r1[wid] = s; r2[wid] = ss; }
    __syncthreads();
    s = r1[0] + r1[1] + r1[2] + r1[3];
    ss = r2[0] + r2[1] + r2[2] + r2[3];
    float mu = s * (1.f / HID);
    float var = ss * (1.f / HID) - mu * mu;
    float rstd = rsqrtf(var + 1e-5f);
    m[(long)t * HID + c] = f2bf((v - mu) * rstd * g[c] + be[c]);
}

// ---------------- MFMA bf16 GEMM, 2-phase double-buffered (T3-minimum) ----------------
// BK=64, two LDS buffers; per tile: barrier (drains prev loads) -> STAGE(next into buf^1)
// -> ds_read+MFMA(buf). One barrier/tile; staging latency hides under compute.
// bf16-out EPIs (0/2/4) use SWAPPED operands -> cvt_pk + b64 LDS writes.
// LDS XOR-swizzled both-sides; block index XCD-swizzled.
template<int EPI>
__global__ __launch_bounds__(256) void gemm_mfma_kernel(
    const u16* __restrict__ A, const u16* __restrict__ Bw,
    const float* __restrict__ bias, const float* __restrict__ hbuf,
    void* __restrict__ outp, int M, int N, int K)
{
    constexpr bool SWAP = (EPI == 0 || EPI == 2 || EPI == 4);
    // dbuf: 2 x (ldsA 16KB + ldsB 16KB) = 64KB; EPI1/5 fp32 epilogue needs 67.6KB
    __shared__ __align__(16) char smem[(EPI == 1 || EPI == 5) ? (128 * 132 * 4) : 65536];
    int tid = threadIdx.x;
    int nbn = N >> 7;
    int cpx = (int)gridDim.x >> 3;
    int bid = ((int)blockIdx.x & 7) * cpx + ((int)blockIdx.x >> 3);   // XCD swizzle
    int bRow = (bid / nbn) << 7;
    int bCol = (bid % nbn) << 7;
    int lane = tid & 63;
    int w = tid >> 6;
    int wr = (w >> 1) << 6;
    int wc = (w & 1) << 6;
    int ln15 = lane & 15;
    int kg = lane >> 4;

    f32x4 acc[4][4] = {};

    int srow = tid >> 3;
    int sg = tid & 7;
    int gsg = sg ^ (srow & 7);                // inverse-swizzled source group
    const u16* gA = A + (long)(bRow + srow) * K + gsg * 8;
    const u16* gB = Bw + (long)(bCol + srow) * K + gsg * 8;

    int nt = K >> 6;

    // prologue: stage tile 0 into buffer 0
    {
        u16* lA = (u16*)smem + srow * 64 + sg * 8;
        u16* lB = (u16*)(smem + 16384) + srow * 64 + sg * 8;
        #pragma unroll
        for (int c = 0; c < 4; ++c) {
            __builtin_amdgcn_global_load_lds(
                (const __attribute__((address_space(1))) void*)(gA + (long)c * 32 * K),
                (__attribute__((address_space(3))) void*)(lA + c * 32 * 64), 16, 0, 0);
            __builtin_amdgcn_global_load_lds(
                (const __attribute__((address_space(1))) void*)(gB + (long)c * 32 * K),
                (__attribute__((address_space(3))) void*)(lB + c * 32 * 64), 16, 0, 0);
        }
    }

    int cur = 0;
    for (int t = 0; t < nt; ++t) {
        __syncthreads();   // drains vmcnt: buf[cur] staged; all waves done with buf[cur^1]
        if (t + 1 < nt) {
            int k0 = (t + 1) << 6;
            u16* lA = (u16*)(smem + (cur ^ 1) * 32768) + srow * 64 + sg * 8;
            u16* lB = (u16*)(smem + (cur ^ 1) * 32768 + 16384) + srow * 64 + sg * 8;
            #pragma unroll
            for (int c = 0; c < 4; ++c) {
                __builtin_amdgcn_global_load_lds(
                    (const __attribute__((address_space(1))) void*)(gA + (long)c * 32 * K + k0),
                    (__attribute__((address_space(3))) void*)(lA + c * 32 * 64), 16, 0, 0);
                __builtin_amdgcn_global_load_lds(
                    (const __attribute__((address_space(1))) void*)(gB + (long)c * 32 * K + k0),
                    (__attribute__((address_space(3))) void*)(lB + c * 32 * 64), 16, 0, 0);
            }
        }
        u16* ldsA = (u16*)(smem + cur * 32768);
        u16* ldsB = (u16*)(smem + cur * 32768 + 16384);
        #pragma unroll
        for (int kk = 0; kk < 64; kk += 32) {
            int gbase = (kk >> 3) + kg;       // logical 16B-group
            bf16x8 av[4], bv[4];
            #pragma unroll
            for (int m = 0; m < 4; ++m) {
                int row = wr + m * 16 + ln15;
                av[m] = *(const bf16x8*)(ldsA + row * 64 + ((gbase ^ (row & 7)) << 3));
            }
            #pragma unroll
            for (int n = 0; n < 4; ++n) {
                int row = wc + n * 16 + ln15;
                bv[n] = *(const bf16x8*)(ldsB + row * 64 + ((gbase ^ (row & 7)) << 3));
            }
            #pragma unroll
            for (int m = 0; m < 4; ++m)
                #pragma unroll
                for (int n = 0; n < 4; ++n) {
                    if (SWAP)
                        acc[m][n] = __builtin_amdgcn_mfma_f32_16x16x32_bf16(bv[n], av[m], acc[m][n], 0, 0, 0);
                    else
                        acc[m][n] = __builtin_amdgcn_mfma_f32_16x16x32_bf16(av[m], bv[n], acc[m][n], 0, 0, 0);
                }
        }
        cur ^= 1;
    }
    __syncthreads();

    if (EPI == 0 || EPI == 2 || EPI == 4) {
        u16* lds2 = (u16*)smem;  // [128 tokens][136]
        #pragma unroll
        for (int n = 0; n < 4; ++n) {
            float4 bn4 = *(const float4*)&bias[bCol + wc + n * 16 + kg * 4];
            #pragma unroll
            for (int m = 0; m < 4; ++m) {
                float v0 = acc[m][n][0] + bn4.x;
                float v1 = acc[m][n][1] + bn4.y;
                float v2 = acc[m][n][2] + bn4.z;
                float v3 = acc[m][n][3] + bn4.w;
                if (EPI == 0) { v0 = fast_gelu(v0); v1 = fast_gelu(v1); v2 = fast_gelu(v2); v3 = fast_gelu(v3); }
                if (EPI == 4) { v0 = sshrink(v0); v1 = sshrink(v1); v2 = sshrink(v2); v3 = sshrink(v3); }
                uint2 pk;
                pk.x = pk_bf16(v0, v1);
                pk.y = pk_bf16(v2, v3);
                int tokenLocal = wr + m * 16 + ln15;
                int nLocal = wc + n * 16 + kg * 4;
                *(uint2*)&lds2[tokenLocal * 136 + nLocal] = pk;
            }
        }
        __syncthreads();
        u16* O = (u16*)outp;
        #pragma unroll
        for (int it = 0; it < 8; ++it) {
            int idx = (it << 8) + tid;
            int row = idx >> 4, c8 = (idx & 15) << 3;
            *(ushort8_t*)&O[(long)(bRow + row) * N + bCol + c8] = *(const ushort8_t*)&lds2[row * 136 + c8];
        }
    } else if (EPI == 5) {
        float* ldsf = (float*)smem;  // [128][132]
        float bn[4];
        #pragma unroll
        for (int n = 0; n < 4; ++n) bn[n] = bias[bCol + wc + n * 16 + ln15];
        #pragma unroll
        for (int m = 0; m < 4; ++m)
            #pragma unroll
            for (int n = 0; n < 4; ++n) {
                int col = wc + n * 16 + ln15;
                #pragma unroll
                for (int r = 0; r < 4; ++r) {
                    int row = wr + m * 16 + kg * 4 + r;
                    ldsf[row * 132 + col] = acc[m][n][r] + bn[n];
                }
            }
        __syncthreads();
        float* O = (float*)outp;
        #pragma unroll
        for (int it = 0; it < 16; ++it) {
            int idx = (it << 8) + tid;
            int row = idx >> 5, c4 = (idx & 31) << 2;
            *(float4*)&O[(long)(bRow + row) * N + bCol + c4] = *(const float4*)&ldsf[row * 132 + c4];
        }
    } else {  // EPI 1
        float* ldsf = (float*)smem;  // [128 cols][132]
        float bn[4];
        #pragma unroll
        for (int n = 0; n < 4; ++n) bn[n] = bias[bCol + wc + n * 16 + ln15];
        #pragma unroll
        for (int m = 0; m < 4; ++m)
            #pragma unroll
            for (int n = 0; n < 4; ++n) {
                int col = wc + n * 16 + ln15;
                float4 vv;
                #pragma unroll
                for (int r = 0; r < 4; ++r) {
                    int row = wr + m * 16 + kg * 4 + r;
                    float v = acc[m][n][r] + bn[n] + hbuf[(long)(bRow + row) * HID + bCol + col];
                    ((float*)&vv)[r] = v;
                }
                *(float4*)&ldsf[col * 132 + wr + m * 16 + kg * 4] = vv;
            }
        __syncthreads();
        float* O = (float*)outp;
        int b = bRow >> 12;
        int s0 = bRow & 4095;
        #pragma unroll
        for (int it = 0; it < 16; ++it) {
            int idx = (it << 8) + tid;
            int oc = idx >> 5, r4 = (idx & 31) << 2;
            *(float4*)&O[((long)(b * HID + bCol + oc)) * HWP + s0 + r4] = *(const float4*)&ldsf[oc * 132 + r4];
        }
    }
}

extern "C" void kernel_launch(void* const* d_in, const int* in_sizes, int n_in,
                              void* d_out, int out_size, void* d_ws, size_t ws_size,
                              hipStream_t stream)
{
    (void)in_sizes; (void)n_in; (void)out_size; (void)ws_size;
    const float* x     = (const float*)d_in[0];
    const float* xp    = (const float*)d_in[1];
    const float* w1    = (const float*)d_in[3];
    const float* b1    = (const float*)d_in[4];
    const float* w2    = (const float*)d_in[5];
    const float* b2    = (const float*)d_in[6];
    const float* w3    = (const float*)d_in[7];
    const float* b3    = (const float*)d_in[8];
    const float* alpha = (const float*)d_in[9];
    const float* g1    = (const float*)d_in[10];
    const float* be1   = (const float*)d_in[11];
    const float* g2    = (const float*)d_in[12];
    const float* be2   = (const float*)d_in[13];
    const float* pw    = (const float*)d_in[14];
    const float* pb    = (const float*)d_in[15];
    const float* fc1w  = (const float*)d_in[16];
    const float* fc1b  = (const float*)d_in[17];
    const float* fc2w  = (const float*)d_in[18];
    const float* fc2b  = (const float*)d_in[19];
    float* out = (float*)d_out;

    float* ws = (float*)d_ws;
    float* S0 = ws + 0 * SLOTF;
    float* S1 = ws + 1 * SLOTF;
    float* S2 = ws + 2 * SLOTF;
    float* S3 = ws + 3 * SLOTF;
    float* S4 = ws + 4 * SLOTF;
    float* S5 = ws + 5 * SLOTF;
    float* S6 = ws + 6 * SLOTF;

    float* RES  = S0;
    u16*   XNB  = (u16*)S1;                // bf16 [32768][128] 8MB (S1-lower)
    u16*   M1x  = (u16*)S2;                // 16MB
    u16*   XF   = (u16*)S3;                // packed [16896][256] 8.7MB
    u16*   X1   = (u16*)S4;                // packed [16896][512] 17.3MB
    u16*   M1p  = (u16*)S2;                // 32MB (M1x dead)
    u16*   PF   = (u16*)S3;                // packed [16896][512] 17.3MB (XF dead)
    u16*   P3   = (u16*)S5;                // packed [16896][512] 17.3MB
    u16*   A2   = (u16*)S2;                // FULL [32768][512] 32MB (M1p dead)
    u16*   O2b  = (u16*)S3;                // full 32MB (PF dead)
    u16*   M2   = (u16*)S2;                // full 32MB (A2 dead)
    float* Hb   = S6;                      // 32MB
    u16*   Mb16 = (u16*)S1;                // 16MB (XNB dead)
    u16*   HIDB = (u16*)S2;                // 128MB spanning S2..S5

    // static region: S1-upper 16MB
    u16* TWB  = (u16*)(S1 + SLOTF / 2);
    u16* TW_F = TWB;                       // fwd hi(16K)+lo(16K)
    u16* TW_I = TWB + 32768;               // inv hi+lo
    u16* W1c  = TWB + 65536;               // 512x256
    u16* W3c  = W1c + 131072;              // 512x512
    u16* W2c  = W3c + 262144;              // 512x512
    u16* WB1  = W2c + 262144;              // 2048x256 bf16 (fc1w)
    u16* WB2  = WB1 + 524288;              // 256x2048 bf16 (fc2w)
    u16* PWB  = WB2 + 524288;              // 256x128 bf16 (proj_w)
    u16* XB   = TWB + 2097152;             // 32768x128 bf16 (8MB), transient

    dim3 blk(256);

    // 0. merged static setup
    setup_kernel<<<1760, blk, 0, stream>>>(w1, w3, w2, fc1w, fc2w, pw,
        TWB, W1c, W3c, W2c, WB1, WB2, PWB);

    // 1. LN1 (bf16 LN'd tokens + bf16 raw tokens) and residual projection (MFMA)
    ln1_kernel<<<512, blk, 0, stream>>>(x, g1, be1, XNB, XB);
    gemm_mfma_kernel<5><<<512, blk, 0, stream>>>(XB, PWB, pb, nullptr,
        (void*)RES, NTOK, HID, CIN);

    // 2-3. forward FFT2 of xn: W-axis (bf16 in) then H-axis; stage-2 keeps kh<=32, packed out
    dftm_kernel<3, 0, 4, 0><<<512, blk, 0, stream>>>(XNB, TW_F, M1x, nullptr,
        1, 524288L, 8192L, 0L, 128L, 0L, 1048576L, 16384L, 0L, 128L, 8192L, 63);
    dftm_kernel<1, 0, 3, 0><<<512, blk, 0, stream>>>(M1x, TW_F, XF, nullptr,
        1, 1048576L, 128L, 0L, 16384L, 8192L, 540672L, 256L, 0L, 16384L, 128L, 32);
    // 4. complex GEMM w1 (K=2*128) on half-plane -> X1 packed bf16
    gemm_mfma_kernel<2><<<528, blk, 0, stream>>>(XF, W1c, b1, nullptr,
        (void*)X1, NTOKH, 512, 256);

    // 5-6. forward FFT2 of x_pangu; stage-2 keeps kh<=32, packed out
    dftm_kernel<2, 0, 4, 0><<<1024, blk, 0, stream>>>(xp, TW_F, M1p, nullptr,
        2, 1048576L, 64L, 524288L, 4096L, 0L, 2097152L, 32768L, 128L, 256L, 16384L, 63);
    dftm_kernel<1, 0, 3, 0><<<1024, blk, 0, stream>>>(M1p, TW_F, PF, nullptr,
        2, 2097152L, 256L, 128L, 32768L, 16384L, 1081344L, 512L, 128L, 32768L, 256L, 32);
    // 7. complex GEMM w3 (K=2*256) on half-plane -> P3 packed bf16
    gemm_mfma_kernel<2><<<528, blk, 0, stream>>>(PF, W3c, b3, nullptr,
        (void*)P3, NTOKH, 512, 512);

    // 8. modulation + channel softmax: half-plane in -> FULL plane out (mirror writes)
    mod_kernel<<<4224, blk, 0, stream>>>(X1, P3, alpha, A2);
    // 9. complex GEMM w2 + softshrink (full plane) -> O2b bf16
    gemm_mfma_kernel<4><<<1024, blk, 0, stream>>>(A2, W2c, b2, nullptr,
        (void*)O2b, NTOK, 512, 512);

    // 10-11. inverse FFT2: H-axis then W-axis (real out, fused +RES; final stage keeps lo)
    dftm_kernel<1, 0, 4, 0><<<1024, blk, 0, stream>>>(O2b, TW_I, M2, nullptr,
        2, 2097152L, 512L, 128L, 32768L, 256L, 2097152L, 256L, 128L, 32768L, 16384L, 63);
    dftm_kernel<1, 1, 4, 1><<<1024, blk, 0, stream>>>(M2, TW_I, Hb, RES,
        2, 2097152L, 32768L, 128L, 256L, 16384L, 1048576L, 16384L, 128L, 256L, 0L, 63);

    // 12. LN2 -> bf16
    ln2_kernel<<<32768, blk, 0, stream>>>(Hb, g2, be2, Mb16);
    // 13. MLP fc1 (MFMA) + fast gelu -> bf16 hidden
    gemm_mfma_kernel<0><<<4096, blk, 0, stream>>>(Mb16, WB1, fc1b, nullptr,
        (void*)HIDB, NTOK, MLPH, HID);
    // 14. MLP fc2 (MFMA) + bias + h, transposed out
    gemm_mfma_kernel<1><<<512, blk, 0, stream>>>(HIDB, WB2, fc2b, Hb,
        (void*)out, NTOK, HID, MLPH);
}

// Round 15
// 331.118 us; speedup vs baseline: 1.0163x; 1.0163x over previous
//
#include <hip/hip_runtime.h>
#include <hip/hip_bf16.h>
#include <math.h>

#define NBATCH 8
#define HWP 4096
#define NTOK 32768
#define NTOKH 16896   // packed half-plane tokens: 8 * 33 * 64
#define CIN 128
#define HID 256
#define MLPH 2048
#define SLOTF 8388608L   // floats per 32MB slot

typedef unsigned short u16;
typedef unsigned char u8;
typedef __attribute__((ext_vector_type(8))) short bf16x8;
typedef __attribute__((ext_vector_type(4))) float f32x4;
typedef __attribute__((ext_vector_type(8))) unsigned short ushort8_t;
typedef __attribute__((ext_vector_type(2))) unsigned long long u64x2;

__device__ __forceinline__ float bf2f(u16 v) { return __uint_as_float(((unsigned)v) << 16); }
__device__ __forceinline__ u16 f2bf(float f) {
    unsigned u = __float_as_uint(f);
    u = u + 0x7fffu + ((u >> 16) & 1u);
    return (u16)(u >> 16);
}
__device__ __forceinline__ u16 bits2bf(unsigned u) {
    u = u + 0x7fffu + ((u >> 16) & 1u);
    return (u16)(u >> 16);
}
// pack 2 fp32 -> u32 of 2 bf16 (hardware cvt_pk)
__device__ __forceinline__ unsigned pk_bf16(float lo, float hi) {
    unsigned r;
    asm("v_cvt_pk_bf16_f32 %0, %1, %2" : "=v"(r) : "v"(lo), "v"(hi));
    return r;
}
// pack 4 fp32 -> u32 of 4 OCP fp8-e4m3
__device__ __forceinline__ unsigned pk4_fp8(float v0, float v1, float v2, float v3) {
    int r = __builtin_amdgcn_cvt_pk_fp8_f32(v0, v1, 0, false);
    r = __builtin_amdgcn_cvt_pk_fp8_f32(v2, v3, r, true);
    return (unsigned)r;
}
__device__ __forceinline__ float sshrink(float v) {
    return v > 0.01f ? v - 0.01f : (v < -0.01f ? v + 0.01f : 0.f);
}
// hardware-native fast gelu
__device__ __forceinline__ float fast_gelu(float v) {
    float z = v * fmaf(0.0713548162726f, v * v, 1.59576912161f);
    float t = __builtin_amdgcn_exp2f(z * -1.44269504088896f);
    return v * __builtin_amdgcn_rcpf(1.f + t);
}

// ---------------- LN1: x (B,128,4096) -> xnb bf16 (B*4096,128) + xb bf16 (B*4096,128) ----------------
__global__ __launch_bounds__(256) void ln1_kernel(const float* __restrict__ x,
    const float* __restrict__ g, const float* __restrict__ be,
    u16* __restrict__ xnb, u16* __restrict__ xb)
{
    __shared__ float xt[CIN][65];
    __shared__ float mu_s[64], rs_s[64];
    int bid = blockIdx.x;
    int b = bid >> 6;
    int t0 = (bid & 63) << 6;
    int tid = threadIdx.x;
    for (int it = 0; it < 32; ++it) {
        int idx = (it << 8) + tid;
        int c = idx >> 6, t = idx & 63;
        xt[c][t] = x[(long)(b * CIN + c) * HWP + t0 + t];
    }
    __syncthreads();
    int tt = tid >> 2, p = tid & 3;
    float s = 0.f, ss = 0.f;
    #pragma unroll
    for (int i = 0; i < 32; ++i) {
        float v = xt[p * 32 + i][tt];
        s += v; ss += v * v;
    }
    s += __shfl_xor(s, 1); ss += __shfl_xor(ss, 1);
    s += __shfl_xor(s, 2); ss += __shfl_xor(ss, 2);
    if (p == 0) {
        float mu = s * (1.f / CIN);
        float var = ss * (1.f / CIN) - mu * mu;
        mu_s[tt] = mu;
        rs_s[tt] = rsqrtf(var + 1e-5f);
    }
    __syncthreads();
    #pragma unroll
    for (int it = 0; it < 16; ++it) {
        int idx = (it << 8) + tid;
        int t = idx >> 6, c2 = (idx & 63) << 1;
        float v0 = (xt[c2][t] - mu_s[t]) * rs_s[t] * g[c2] + be[c2];
        float v1 = (xt[c2 + 1][t] - mu_s[t]) * rs_s[t] * g[c2 + 1] + be[c2 + 1];
        *(unsigned*)&xnb[((long)b * HWP + t0 + t) * CIN + c2] = pk_bf16(v0, v1);
    }
    #pragma unroll
    for (int it = 0; it < 8; ++it) {
        int idx = (it << 8) + tid;
        int t = idx >> 5, c4 = (idx & 31) << 2;
        uint2 pk;
        pk.x = pk_bf16(xt[c4 + 0][t], xt[c4 + 1][t]);
        pk.y = pk_bf16(xt[c4 + 2][t], xt[c4 + 3][t]);
        *(uint2*)&xb[((long)b * HWP + t0 + t) * CIN + c4] = pk;
    }
}

// ---------------- merged static setup: twiddle tables + all weight conversions ----------------
__device__ __forceinline__ void wcvt_body(const float* __restrict__ w, int K,
    u16* __restrict__ out, int idx)
{
    int k = idx >> 8, o = idx & 255;
    float w0 = w[k * 256 + o];
    float w1v = w[K * 256 + k * 256 + o];
    long K2 = 2L * K;
    out[(long)o * K2 + k] = f2bf(w0);
    out[(long)o * K2 + K + k] = f2bf(-w1v);
    out[(long)(256 + o) * K2 + k] = f2bf(w1v);
    out[(long)(256 + o) * K2 + K + k] = f2bf(w0);
}
__device__ __forceinline__ void f2bf_body(const float* __restrict__ in,
    u16* __restrict__ out, int i)
{
    float4 v = *(const float4*)&in[i];
    ushort4 o;
    o.x = f2bf(v.x); o.y = f2bf(v.y); o.z = f2bf(v.z); o.w = f2bf(v.w);
    *(ushort4*)&out[i] = o;
}
__global__ __launch_bounds__(256) void setup_kernel(
    const float* __restrict__ w1, const float* __restrict__ w3,
    const float* __restrict__ w2, const float* __restrict__ fc1w,
    const float* __restrict__ fc2w, const float* __restrict__ pw,
    u16* __restrict__ TWB, u16* __restrict__ W1c, u16* __restrict__ W3c,
    u16* __restrict__ W2c, u16* __restrict__ WB1, unsigned* __restrict__ WB2F,
    u16* __restrict__ PWB)
{
    int bid = blockIdx.x, tid = threadIdx.x;
    if (bid < 64) {
        int idx = bid * 256 + tid;            // n*128 + kcol
        int n = idx >> 7, kcol = idx & 127;
        int j = kcol & 63, p = kcol >> 6;
        int np = n & 63, q = n >> 6;
        float th = 6.283185307179586f * (float)((j * np) & 63) / 64.f;
        float sv, cv;
        sincosf(th, &sv, &cv);
        float fw = (q == 0) ? (p == 0 ? cv : sv) : (p == 0 ? -sv : cv);
        float iv = (q == 0) ? (p == 0 ? cv : -sv) : (p == 0 ? sv : cv);
        fw *= 0.125f; iv *= 0.125f;
        u16 fh = f2bf(fw), ih = f2bf(iv);
        TWB[idx] = fh;
        TWB[16384 + idx] = f2bf(fw - bf2f(fh));
        TWB[32768 + idx] = ih;
        TWB[49152 + idx] = f2bf(iv - bf2f(ih));
    } else if (bid < 192) {
        wcvt_body(w1, 128, W1c, (bid - 64) * 256 + tid);
    } else if (bid < 448) {
        wcvt_body(w3, 256, W3c, (bid - 192) * 256 + tid);
    } else if (bid < 704) {
        wcvt_body(w2, 256, W2c, (bid - 448) * 256 + tid);
    } else if (bid < 1216) {
        f2bf_body(fc1w, WB1, ((bid - 704) * 256 + tid) * 4);
    } else if (bid < 1728) {
        int i = ((bid - 1216) * 256 + tid) * 4;
        float4 v = *(const float4*)&fc2w[i];
        WB2F[i >> 2] = pk4_fp8(v.x, v.y, v.z, v.w);
    } else {
        f2bf_body(pw, PWB, ((bid - 1728) * 256 + tid) * 4);
    }
}

// ---------------- MFMA 64-pt DFT along one axis ----------------
// INMODE 0: fp32 in, c-contig runs, real (K=64)
// INMODE 1: bf16 in, c-contig runs, cplx (K=128)
// INMODE 2: fp32 in, j-contig rows, real (K=64)
// INMODE 3: bf16 in, c-contig runs, real (K=64)
template<int INMODE, int REALOUT, int NT, int USELO>
__global__ __launch_bounds__(256) void dftm_kernel(
    const void* __restrict__ inp, const u16* __restrict__ tw,
    void* __restrict__ outp, const float* __restrict__ addend,
    int nch, long IB, long IK, long IC, long JS, long PS,
    long OB, long OK, long OC, long KS, long PS2, int kmax)
{
    constexpr int K = (INMODE == 1) ? 128 : 64;
    constexpr int AST = (K == 128) ? 136 : 72;
    constexpr int MFR = REALOUT ? 2 : 4;
    __shared__ __align__(16) u16 smem[128 * 136];
    int tid = threadIdx.x;
    int lane = tid & 63;
    int bid = blockIdx.x;
    int b = bid / (64 * nch);
    int rem = bid % (64 * nch);
    int keep = rem / nch;
    int ch = rem % nch;
    long ibase = b * IB + keep * IK + ch * IC;
    long obase = b * OB + keep * OK + ch * OC;

    if (INMODE == 0) {
        const float* inF = (const float*)inp;
        #pragma unroll
        for (int it = 0; it < 8; ++it) {
            int idx = (it << 8) + tid;
            int j = idx >> 5, c4 = (idx & 31) << 2;
            u64x2 v = *(const u64x2*)(inF + ibase + (long)j * JS + c4);
            #pragma unroll
            for (int i = 0; i < 4; ++i) {
                int vv = (i + lane) & 3;
                unsigned long long q = (vv & 2) ? v.y : v.x;
                unsigned fb = (unsigned)(q >> ((vv & 1) << 5));
                smem[(c4 + vv) * AST + j] = bits2bf(fb);
            }
        }
    } else if (INMODE == 1) {
        const u16* inU = (const u16*)inp;
        #pragma unroll
        for (int it = 0; it < 8; ++it) {
            int idx = (it << 8) + tid;
            int run = idx >> 4, c8 = (idx & 15) << 3;
            int j = run >> 1, p = run & 1;
            u64x2 v = *(const u64x2*)(inU + ibase + (long)j * JS + (long)p * PS + c8);
            int col = p * 64 + j;
            #pragma unroll
            for (int i = 0; i < 8; ++i) {
                int vv = (i + lane) & 7;
                unsigned long long q = (vv & 4) ? v.y : v.x;
                u16 val = (u16)(q >> ((vv & 3) << 4));
                smem[(c8 + vv) * AST + col] = val;
            }
        }
    } else if (INMODE == 3) {
        const u16* inU = (const u16*)inp;
        #pragma unroll
        for (int it = 0; it < 4; ++it) {
            int idx = (it << 8) + tid;
            int j = idx >> 4, c8 = (idx & 15) << 3;
            u64x2 v = *(const u64x2*)(inU + ibase + (long)j * JS + c8);
            #pragma unroll
            for (int i = 0; i < 8; ++i) {
                int vv = (i + lane) & 7;
                unsigned long long q = (vv & 4) ? v.y : v.x;
                u16 val = (u16)(q >> ((vv & 3) << 4));
                smem[(c8 + vv) * AST + j] = val;
            }
        }
    } else {
        const float* inF = (const float*)inp;
        #pragma unroll
        for (int it = 0; it < 8; ++it) {
            int idx = (it << 8) + tid;
            int row = idx >> 4, j4 = (idx & 15) << 2;
            u64x2 v = *(const u64x2*)(inF + ibase + (long)row * JS + j4);
            ushort4 o;
            o.x = bits2bf((unsigned)v.x);
            o.y = bits2bf((unsigned)(v.x >> 32));
            o.z = bits2bf((unsigned)v.y);
            o.w = bits2bf((unsigned)(v.y >> 32));
            *(ushort4*)&smem[row * AST + j4] = o;
        }
    }
    __syncthreads();

    int w = tid >> 6;
    int ln15 = lane & 15, kg = lane >> 4;
    int wrow = REALOUT ? (w << 5) : ((w >> 1) << 6);
    int wcol = REALOUT ? 0 : ((w & 1) << 6);
    f32x4 acc[MFR][NT] = {};
    #pragma unroll
    for (int kk = 0; kk < K / 32; ++kk) {
        bf16x8 av[MFR];
        #pragma unroll
        for (int m = 0; m < MFR; ++m)
            av[m] = *(const bf16x8*)&smem[(wrow + m * 16 + ln15) * AST + kk * 32 + kg * 8];
        #pragma unroll
        for (int n = 0; n < NT; ++n) {
            const u16* tb = tw + (wcol + n * 16 + ln15) * 128 + kk * 32 + kg * 8;
            bf16x8 bh = *(const bf16x8*)tb;
            #pragma unroll
            for (int m = 0; m < MFR; ++m)
                acc[m][n] = __builtin_amdgcn_mfma_f32_16x16x32_bf16(av[m], bh, acc[m][n], 0, 0, 0);
            if (USELO) {
                bf16x8 bl = *(const bf16x8*)(tb + 16384);
                #pragma unroll
                for (int m = 0; m < MFR; ++m)
                    acc[m][n] = __builtin_amdgcn_mfma_f32_16x16x32_bf16(av[m], bl, acc[m][n], 0, 0, 0);
            }
        }
    }
    __syncthreads();

    if (REALOUT == 0) {
        #pragma unroll
        for (int m = 0; m < MFR; ++m)
            #pragma unroll
            for (int n = 0; n < NT; ++n) {
                int base = (wcol + n * 16 + ln15) * 136 + wrow + m * 16 + kg * 4;
                uint2 pk;
                pk.x = pk_bf16(acc[m][n][0], acc[m][n][1]);
                pk.y = pk_bf16(acc[m][n][2], acc[m][n][3]);
                *(uint2*)&smem[base] = pk;
            }
        __syncthreads();
        u16* outU = (u16*)outp;
        #pragma unroll
        for (int it = 0; it < 8; ++it) {
            int idx = (it << 8) + tid;
            int n = idx >> 4, c8 = (idx & 15) << 3;
            int k = n & 63, p = n >> 6;
            if (k <= kmax)
                *(ushort8_t*)&outU[obase + (long)k * KS + (long)p * PS2 + c8] =
                    *(const ushort8_t*)&smem[n * 136 + c8];
        }
    } else {
        float* ef = (float*)smem;  // [64][132]
        #pragma unroll
        for (int m = 0; m < MFR; ++m)
            #pragma unroll
            for (int n = 0; n < NT; ++n) {
                float4 vv = make_float4(acc[m][n][0], acc[m][n][1], acc[m][n][2], acc[m][n][3]);
                *(float4*)&ef[(n * 16 + ln15) * 132 + wrow + m * 16 + kg * 4] = vv;
            }
        __syncthreads();
        float* outF = (float*)outp;
        #pragma unroll
        for (int it = 0; it < 8; ++it) {
            int idx = (it << 8) + tid;
            int k = idx >> 5, c4 = (idx & 31) << 2;
            long a = obase + (long)k * KS + c4;
            float4 v = *(const float4*)&ef[k * 132 + c4];
            float4 rv = *(const float4*)&addend[a];
            v.x += rv.x; v.y += rv.y; v.z += rv.z; v.w += rv.w;
            *(float4*)&outF[a] = v;
        }
    }
}

// ---------------- modulation + channel softmax: half-plane in, full plane out ----------------
__global__ __launch_bounds__(256) void mod_kernel(
    const u16* __restrict__ x1, const u16* __restrict__ p3,
    const float* __restrict__ alpha, u16* __restrict__ a2)
{
    int tid = threadIdx.x;
    int lane = tid & 63;
    int wv = tid >> 6;
    int tp = blockIdx.x * 4 + wv;          // packed token, 0..16895
    int b = tp / 2112;
    int r = tp - b * 2112;
    int kh = r >> 6, kw = r & 63;
    long ibase = (long)tp * 512 + lane * 4;
    ushort4 xr4 = *(const ushort4*)&x1[ibase];
    ushort4 xi4 = *(const ushort4*)&x1[ibase + 256];
    ushort4 pr4 = *(const ushort4*)&p3[ibase];
    ushort4 pi4 = *(const ushort4*)&p3[ibase + 256];
    float4 al4 = *(const float4*)&alpha[lane * 4];
    u16 xru[4] = {xr4.x, xr4.y, xr4.z, xr4.w};
    u16 xiu[4] = {xi4.x, xi4.y, xi4.z, xi4.w};
    u16 pru[4] = {pr4.x, pr4.y, pr4.z, pr4.w};
    u16 piu[4] = {pi4.x, pi4.y, pi4.z, pi4.w};
    float alv[4] = {al4.x, al4.y, al4.z, al4.w};
    float mo[4], oc[4], os[4], sim[4];
    #pragma unroll
    for (int q = 0; q < 4; ++q) {
        float xr = bf2f(xru[q]), xi = bf2f(xiu[q]);
        float pr = bf2f(pru[q]), pi = bf2f(piu[q]);
        float al = alv[q];
        float m = __builtin_amdgcn_sqrtf(xr * xr + xi * xi);
        float mp = __builtin_amdgcn_sqrtf(pr * pr + pi * pi);
        float cx, sx, cp, sp;
        if (m > 0.f) { float rr = __builtin_amdgcn_rcpf(m); cx = xr * rr; sx = xi * rr; }
        else { cx = 1.f; sx = 0.f; }
        if (mp > 0.f) { float rr = __builtin_amdgcn_rcpf(mp); cp = pr * rr; sp = pi * rr; }
        else { cp = 1.f; sp = 0.f; }
        float sc = al * cx + (1.f - al) * cp;
        float ssn = al * sx + (1.f - al) * sp;
        float rn = __builtin_amdgcn_rsqf(sc * sc + ssn * ssn + 1e-8f);
        mo[q] = m;
        oc[q] = sc * rn;
        os[q] = ssn * rn;
        float cross = pr * xr + pi * xi;
        sim[q] = cross * __builtin_amdgcn_rcpf(mp * m + 1e-8f);
    }
    float mv = fmaxf(fmaxf(sim[0], sim[1]), fmaxf(sim[2], sim[3]));
    #pragma unroll
    for (int off = 1; off < 64; off <<= 1) mv = fmaxf(mv, __shfl_xor(mv, off));
    float e[4];
    float sum = 0.f;
    #pragma unroll
    for (int q = 0; q < 4; ++q) {
        e[q] = __builtin_amdgcn_exp2f((sim[q] - mv) * 1.44269504088896f);
        sum += e[q];
    }
    #pragma unroll
    for (int off = 1; off < 64; off <<= 1) sum += __shfl_xor(sum, off);
    float rs = __builtin_amdgcn_rcpf(sum);
    float orf[4], ipf[4], imf[4];
    #pragma unroll
    for (int q = 0; q < 4; ++q) {
        float mag = mo[q] * e[q] * rs;
        orf[q] = fmaxf(mag * oc[q], 0.f);
        ipf[q] = fmaxf(mag * os[q], 0.f);
        imf[q] = fmaxf(-mag * os[q], 0.f);
    }
    uint2 o_r, o_ip, o_im;
    o_r.x = pk_bf16(orf[0], orf[1]);  o_r.y = pk_bf16(orf[2], orf[3]);
    o_ip.x = pk_bf16(ipf[0], ipf[1]); o_ip.y = pk_bf16(ipf[2], ipf[3]);
    o_im.x = pk_bf16(imf[0], imf[1]); o_im.y = pk_bf16(imf[2], imf[3]);
    long pbase = ((long)b * 4096 + kh * 64 + kw) * 512 + lane * 4;
    *(uint2*)&a2[pbase] = o_r;
    *(uint2*)&a2[pbase + 256] = o_ip;
    if (kh >= 1 && kh <= 31) {
        long mbase = ((long)b * 4096 + (64 - kh) * 64 + ((64 - kw) & 63)) * 512 + lane * 4;
        *(uint2*)&a2[mbase] = o_r;
        *(uint2*)&a2[mbase + 256] = o_im;
    }
}

// ---------------- LN2 over 256 channels -> bf16 out ----------------
__global__ __launch_bounds__(256) void ln2_kernel(const float* __restrict__ h,
    const float* __restrict__ g, const float* __restrict__ be, u16* __restrict__ m)
{
    int t = blockIdx.x, c = threadIdx.x;
    float v = h[(long)t * HID + c];
    float s = v, ss = v * v;
    #pragma unroll
    for (int off = 1; off < 64; off <<= 1) { s += __shfl_xor(s, off); ss += __shfl_xor(ss, off); }
    __shared__ float r1[4], r2[4];
    int wid = c >> 6;
    if ((c & 63) == 0) { r1[wid] = s; r2[wid] = ss; }
    __syncthreads();
    s = r1[0] + r1[1] + r1[2] + r1[3];
    ss = r2[0] + r2[1] + r2[2] + r2[3];
    float mu = s * (1.f / HID);
    float var = ss * (1.f / HID) - mu * mu;
    float rstd = rsqrtf(var + 1e-5f);
    m[(long)t * HID + c] = f2bf((v - mu) * rstd * g[c] + be[c]);
}

// ---------------- MFMA bf16 GEMM (single-buffer, R13-proven) ----------------
// EPI 0: bf16 out = fast-gelu(C + bias)    EPI 2: bf16 out = C + bias
// EPI 4: bf16 out = softshrink(C + bias)   EPI 5: fp32 out = C + bias
// EPI 6: fp8 out = fast-gelu(C + bias)     (mlp1 -> fp8 hidden)
// bf16/fp8-out EPIs use SWAPPED operands -> packed stores.
template<int EPI, int BK>
__global__ __launch_bounds__(256) void gemm_mfma_kernel(
    const u16* __restrict__ A, const u16* __restrict__ Bw,
    const float* __restrict__ bias, const float* __restrict__ hbuf,
    void* __restrict__ outp, int M, int N, int K)
{
    constexpr bool SWAP = (EPI == 0 || EPI == 2 || EPI == 4 || EPI == 6);
    __shared__ __align__(16) char smem[(EPI == 5) ? (128 * 132 * 4) : (128 * 136 * 2)];
    u16* ldsA = (u16*)smem;                     // [128][BK] swizzled
    u16* ldsB = (u16*)(smem + 128 * BK * 2);    // [128][BK] swizzled
    int tid = threadIdx.x;
    int nbn = N >> 7;
    int cpx = (int)gridDim.x >> 3;
    int bid = ((int)blockIdx.x & 7) * cpx + ((int)blockIdx.x >> 3);   // XCD swizzle
    int bRow = (bid / nbn) << 7;
    int bCol = (bid % nbn) << 7;
    int lane = tid & 63;
    int w = tid >> 6;
    int wr = (w >> 1) << 6;
    int wc = (w & 1) << 6;
    int ln15 = lane & 15;
    int kg = lane >> 4;

    f32x4 acc[4][4] = {};

    constexpr int GR = BK / 8;                // 16B-groups per row
    int srow = tid / GR;
    int sg = tid % GR;
    int gsg = sg ^ (srow & 7);                // inverse-swizzled source group
    const u16* gA = A + (long)(bRow + srow) * K + gsg * 8;
    const u16* gB = Bw + (long)(bCol + srow) * K + gsg * 8;
    u16* lA = ldsA + srow * BK + sg * 8;
    u16* lB = ldsB + srow * BK + sg * 8;
    constexpr int RPR = 256 / GR;             // rows per staging round
    constexpr int NCH = 128 / RPR;            // staging rounds per tile

    for (int k0 = 0; k0 < K; k0 += BK) {
        __syncthreads();
        #pragma unroll
        for (int c = 0; c < NCH; ++c) {
            __builtin_amdgcn_global_load_lds(
                (const __attribute__((address_space(1))) void*)(gA + (long)c * RPR * K + k0),
                (__attribute__((address_space(3))) void*)(lA + c * RPR * BK), 16, 0, 0);
            __builtin_amdgcn_global_load_lds(
                (const __attribute__((address_space(1))) void*)(gB + (long)c * RPR * K + k0),
                (__attribute__((address_space(3))) void*)(lB + c * RPR * BK), 16, 0, 0);
        }
        __syncthreads();
        #pragma unroll
        for (int kk = 0; kk < BK; kk += 32) {
            int gbase = (kk >> 3) + kg;       // logical 16B-group
            bf16x8 av[4], bv[4];
            #pragma unroll
            for (int m = 0; m < 4; ++m) {
                int row = wr + m * 16 + ln15;
                av[m] = *(const bf16x8*)(ldsA + row * BK + ((gbase ^ (row & 7)) << 3));
            }
            #pragma unroll
            for (int n = 0; n < 4; ++n) {
                int row = wc + n * 16 + ln15;
                bv[n] = *(const bf16x8*)(ldsB + row * BK + ((gbase ^ (row & 7)) << 3));
            }
            #pragma unroll
            for (int m = 0; m < 4; ++m)
                #pragma unroll
                for (int n = 0; n < 4; ++n) {
                    if (SWAP)
                        acc[m][n] = __builtin_amdgcn_mfma_f32_16x16x32_bf16(bv[n], av[m], acc[m][n], 0, 0, 0);
                    else
                        acc[m][n] = __builtin_amdgcn_mfma_f32_16x16x32_bf16(av[m], bv[n], acc[m][n], 0, 0, 0);
                }
        }
    }
    __syncthreads();

    if (EPI == 0 || EPI == 2 || EPI == 4) {
        u16* lds2 = (u16*)smem;  // [128 tokens][136]
        #pragma unroll
        for (int n = 0; n < 4; ++n) {
            float4 bn4 = *(const float4*)&bias[bCol + wc + n * 16 + kg * 4];
            #pragma unroll
            for (int m = 0; m < 4; ++m) {
                float v0 = acc[m][n][0] + bn4.x;
                float v1 = acc[m][n][1] + bn4.y;
                float v2 = acc[m][n][2] + bn4.z;
                float v3 = acc[m][n][3] + bn4.w;
                if (EPI == 0) { v0 = fast_gelu(v0); v1 = fast_gelu(v1); v2 = fast_gelu(v2); v3 = fast_gelu(v3); }
                if (EPI == 4) { v0 = sshrink(v0); v1 = sshrink(v1); v2 = sshrink(v2); v3 = sshrink(v3); }
                uint2 pk;
                pk.x = pk_bf16(v0, v1);
                pk.y = pk_bf16(v2, v3);
                int tokenLocal = wr + m * 16 + ln15;
                int nLocal = wc + n * 16 + kg * 4;
                *(uint2*)&lds2[tokenLocal * 136 + nLocal] = pk;
            }
        }
        __syncthreads();
        u16* O = (u16*)outp;
        #pragma unroll
        for (int it = 0; it < 8; ++it) {
            int idx = (it << 8) + tid;
            int row = idx >> 4, c8 = (idx & 15) << 3;
            *(ushort8_t*)&O[(long)(bRow + row) * N + bCol + c8] = *(const ushort8_t*)&lds2[row * 136 + c8];
        }
    } else if (EPI == 6) {
        unsigned* lds2 = (unsigned*)smem;  // [128 tokens][36] u32 (fp8x4 packed)
        #pragma unroll
        for (int n = 0; n < 4; ++n) {
            float4 bn4 = *(const float4*)&bias[bCol + wc + n * 16 + kg * 4];
            #pragma unroll
            for (int m = 0; m < 4; ++m) {
                float v0 = fast_gelu(acc[m][n][0] + bn4.x);
                float v1 = fast_gelu(acc[m][n][1] + bn4.y);
                float v2 = fast_gelu(acc[m][n][2] + bn4.z);
                float v3 = fast_gelu(acc[m][n][3] + bn4.w);
                int tokenLocal = wr + m * 16 + ln15;
                int nLocal = wc + n * 16 + kg * 4;
                lds2[tokenLocal * 36 + (nLocal >> 2)] = pk4_fp8(v0, v1, v2, v3);
            }
        }
        __syncthreads();
        u8* O = (u8*)outp;
        #pragma unroll
        for (int it = 0; it < 4; ++it) {
            int idx = (it << 8) + tid;
            int row = idx >> 3, u = idx & 7;
            uint4 vv = *(const uint4*)&lds2[row * 36 + u * 4];
            *(uint4*)&O[(long)(bRow + row) * (long)N + bCol + u * 16] = vv;
        }
    } else {  // EPI 5
        float* ldsf = (float*)smem;  // [128][132]
        float bn[4];
        #pragma unroll
        for (int n = 0; n < 4; ++n) bn[n] = bias[bCol + wc + n * 16 + ln15];
        #pragma unroll
        for (int m = 0; m < 4; ++m)
            #pragma unroll
            for (int n = 0; n < 4; ++n) {
                int col = wc + n * 16 + ln15;
                #pragma unroll
                for (int r = 0; r < 4; ++r) {
                    int row = wr + m * 16 + kg * 4 + r;
                    ldsf[row * 132 + col] = acc[m][n][r] + bn[n];
                }
            }
        __syncthreads();
        float* O = (float*)outp;
        #pragma unroll
        for (int it = 0; it < 16; ++it) {
            int idx = (it << 8) + tid;
            int row = idx >> 5, c4 = (idx & 31) << 2;
            *(float4*)&O[(long)(bRow + row) * N + bCol + c4] = *(const float4*)&ldsf[row * 132 + c4];
        }
    }
}

// ---------------- mlp2: fp8 x fp8 MFMA GEMM + bias + Hb, transposed fp32 out ----------------
// A = hidden fp8 [32768][2048], Bw = fc2w fp8 [256][2048]; tile 128x128, BK=64 bytes.
__global__ __launch_bounds__(256) void mlp2_fp8_kernel(
    const u8* __restrict__ A, const u8* __restrict__ Bw,
    const float* __restrict__ bias, const float* __restrict__ hbuf,
    float* __restrict__ out)
{
    __shared__ __align__(16) char smem[128 * 132 * 4];
    u8* ldsA = (u8*)smem;            // [128][64]
    u8* ldsB = (u8*)(smem + 8192);   // [128][64]
    int tid = threadIdx.x;
    int cpx = (int)gridDim.x >> 3;
    int bid = ((int)blockIdx.x & 7) * cpx + ((int)blockIdx.x >> 3);   // XCD swizzle
    int bRow = (bid >> 1) << 7;
    int bCol = (bid & 1) << 7;
    int lane = tid & 63;
    int w = tid >> 6;
    int wr = (w >> 1) << 6;
    int wc = (w & 1) << 6;
    int ln15 = lane & 15;
    int kg = lane >> 4;

    f32x4 acc[4][4] = {};

    int srow = tid >> 2;             // 64 rows per staging round (4 x 16B groups/row)
    int sg = tid & 3;
    int gsg = sg ^ (srow & 3);       // inverse-swizzled source group
    const u8* gA = A + (long)(bRow + srow) * MLPH + gsg * 16;
    const u8* gB = Bw + (long)(bCol + srow) * MLPH + gsg * 16;
    u8* lA = ldsA + srow * 64 + sg * 16;
    u8* lB = ldsB + srow * 64 + sg * 16;

    for (int k0 = 0; k0 < MLPH; k0 += 64) {
        __syncthreads();
        #pragma unroll
        for (int c = 0; c < 2; ++c) {
            __builtin_amdgcn_global_load_lds(
                (const __attribute__((address_space(1))) void*)(gA + (long)c * 64 * MLPH + k0),
                (__attribute__((address_space(3))) void*)(lA + c * 64 * 64), 16, 0, 0);
            __builtin_amdgcn_global_load_lds(
                (const __attribute__((address_space(1))) void*)(gB + (long)c * 64 * MLPH + k0),
                (__attribute__((address_space(3))) void*)(lB + c * 64 * 64), 16, 0, 0);
        }
        __syncthreads();
        #pragma unroll
        for (int kk = 0; kk < 64; kk += 32) {
            int boff = kk + kg * 8;
            long long av[4], bv[4];
            #pragma unroll
            for (int m = 0; m < 4; ++m) {
                int row = wr + m * 16 + ln15;
                av[m] = *(const long long*)(ldsA + row * 64 + (((boff >> 4) ^ (row & 3)) << 4) + (boff & 15));
            }
            #pragma unroll
            for (int n = 0; n < 4; ++n) {
                int row = wc + n * 16 + ln15;
                bv[n] = *(const long long*)(ldsB + row * 64 + (((boff >> 4) ^ (row & 3)) << 4) + (boff & 15));
            }
            #pragma unroll
            for (int m = 0; m < 4; ++m)
                #pragma unroll
                for (int n = 0; n < 4; ++n)
                    acc[m][n] = __builtin_amdgcn_mfma_f32_16x16x32_fp8_fp8(av[m], bv[n], acc[m][n], 0, 0, 0);
        }
    }
    __syncthreads();

    // epilogue: + bias + Hb, transposed (B,C,H,W) store
    float* ldsf = (float*)smem;  // [128 cols][132]
    float bn[4];
    #pragma unroll
    for (int n = 0; n < 4; ++n) bn[n] = bias[bCol + wc + n * 16 + ln15];
    #pragma unroll
    for (int m = 0; m < 4; ++m)
        #pragma unroll
        for (int n = 0; n < 4; ++n) {
            int col = wc + n * 16 + ln15;
            float4 vv;
            #pragma unroll
            for (int r = 0; r < 4; ++r) {
                int row = wr + m * 16 + kg * 4 + r;
                float v = acc[m][n][r] + bn[n] + hbuf[(long)(bRow + row) * HID + bCol + col];
                ((float*)&vv)[r] = v;
            }
            *(float4*)&ldsf[col * 132 + wr + m * 16 + kg * 4] = vv;
        }
    __syncthreads();
    int b = bRow >> 12;
    int s0 = bRow & 4095;
    #pragma unroll
    for (int it = 0; it < 16; ++it) {
        int idx = (it << 8) + tid;
        int oc = idx >> 5, r4 = (idx & 31) << 2;
        *(float4*)&out[((long)(b * HID + bCol + oc)) * HWP + s0 + r4] = *(const float4*)&ldsf[oc * 132 + r4];
    }
}

extern "C" void kernel_launch(void* const* d_in, const int* in_sizes, int n_in,
                              void* d_out, int out_size, void* d_ws, size_t ws_size,
                              hipStream_t stream)
{
    (void)in_sizes; (void)n_in; (void)out_size; (void)ws_size;
    const float* x     = (const float*)d_in[0];
    const float* xp    = (const float*)d_in[1];
    const float* w1    = (const float*)d_in[3];
    const float* b1    = (const float*)d_in[4];
    const float* w2    = (const float*)d_in[5];
    const float* b2    = (const float*)d_in[6];
    const float* w3    = (const float*)d_in[7];
    const float* b3    = (const float*)d_in[8];
    const float* alpha = (const float*)d_in[9];
    const float* g1    = (const float*)d_in[10];
    const float* be1   = (const float*)d_in[11];
    const float* g2    = (const float*)d_in[12];
    const float* be2   = (const float*)d_in[13];
    const float* pw    = (const float*)d_in[14];
    const float* pb    = (const float*)d_in[15];
    const float* fc1w  = (const float*)d_in[16];
    const float* fc1b  = (const float*)d_in[17];
    const float* fc2w  = (const float*)d_in[18];
    const float* fc2b  = (const float*)d_in[19];
    float* out = (float*)d_out;

    float* ws = (float*)d_ws;
    float* S0 = ws + 0 * SLOTF;
    float* S1 = ws + 1 * SLOTF;
    float* S2 = ws + 2 * SLOTF;
    float* S3 = ws + 3 * SLOTF;
    float* S4 = ws + 4 * SLOTF;
    float* S5 = ws + 5 * SLOTF;
    float* S6 = ws + 6 * SLOTF;

    float* RES  = S0;
    u16*   XNB  = (u16*)S1;                // bf16 [32768][128] 8MB (S1-lower)
    u16*   M1x  = (u16*)S2;                // 16MB
    u16*   XF   = (u16*)S3;                // packed [16896][256] 8.7MB
    u16*   X1   = (u16*)S4;                // packed [16896][512] 17.3MB
    u16*   M1p  = (u16*)S2;                // 32MB (M1x dead)
    u16*   PF   = (u16*)S3;                // packed [16896][512] 17.3MB (XF dead)
    u16*   P3   = (u16*)S5;                // packed [16896][512] 17.3MB
    u16*   A2   = (u16*)S2;                // FULL [32768][512] 32MB (M1p dead)
    u16*   O2b  = (u16*)S3;                // full 32MB (PF dead)
    u16*   M2   = (u16*)S2;                // full 32MB (A2 dead)
    float* Hb   = S6;                      // 32MB
    u16*   Mb16 = (u16*)S1;                // 16MB (XNB dead)
    u8*    HIDF8 = (u8*)S2;                // fp8 hidden 67MB spanning S2..S4

    // static region: S1-upper 16MB
    u16* TWB  = (u16*)(S1 + SLOTF / 2);
    u16* TW_F = TWB;                       // fwd hi(16K)+lo(16K)
    u16* TW_I = TWB + 32768;               // inv hi+lo
    u16* W1c  = TWB + 65536;               // 512x256
    u16* W3c  = W1c + 131072;              // 512x512
    u16* W2c  = W3c + 262144;              // 512x512
    u16* WB1  = W2c + 262144;              // 2048x256 bf16 (fc1w)
    unsigned* WB2F = (unsigned*)(WB1 + 524288);  // 256x2048 fp8 (fc2w), 512KB
    u16* PWB  = WB1 + 524288 + 524288;     // 256x128 bf16 (proj_w)
    u16* XB   = TWB + 2097152;             // 32768x128 bf16 (8MB), transient

    dim3 blk(256);

    // 0. merged static setup
    setup_kernel<<<1760, blk, 0, stream>>>(w1, w3, w2, fc1w, fc2w, pw,
        TWB, W1c, W3c, W2c, WB1, WB2F, PWB);

    // 1. LN1 (bf16 LN'd tokens + bf16 raw tokens) and residual projection (MFMA)
    ln1_kernel<<<512, blk, 0, stream>>>(x, g1, be1, XNB, XB);
    gemm_mfma_kernel<5, 128><<<512, blk, 0, stream>>>(XB, PWB, pb, nullptr,
        (void*)RES, NTOK, HID, CIN);

    // 2-3. forward FFT2 of xn: W-axis (bf16 in) then H-axis; stage-2 keeps kh<=32, packed out
    dftm_kernel<3, 0, 4, 0><<<512, blk, 0, stream>>>(XNB, TW_F, M1x, nullptr,
        1, 524288L, 8192L, 0L, 128L, 0L, 1048576L, 16384L, 0L, 128L, 8192L, 63);
    dftm_kernel<1, 0, 3, 0><<<512, blk, 0, stream>>>(M1x, TW_F, XF, nullptr,
        1, 1048576L, 128L, 0L, 16384L, 8192L, 540672L, 256L, 0L, 16384L, 128L, 32);
    // 4. complex GEMM w1 (K=2*128) on half-plane -> X1 packed bf16
    gemm_mfma_kernel<2, 64><<<528, blk, 0, stream>>>(XF, W1c, b1, nullptr,
        (void*)X1, NTOKH, 512, 256);

    // 5-6. forward FFT2 of x_pangu; stage-2 keeps kh<=32, packed out
    dftm_kernel<2, 0, 4, 0><<<1024, blk, 0, stream>>>(xp, TW_F, M1p, nullptr,
        2, 1048576L, 64L, 524288L, 4096L, 0L, 2097152L, 32768L, 128L, 256L, 16384L, 63);
    dftm_kernel<1, 0, 3, 0><<<1024, blk, 0, stream>>>(M1p, TW_F, PF, nullptr,
        2, 2097152L, 256L, 128L, 32768L, 16384L, 1081344L, 512L, 128L, 32768L, 256L, 32);
    // 7. complex GEMM w3 (K=2*256) on half-plane -> P3 packed bf16
    gemm_mfma_kernel<2, 64><<<528, blk, 0, stream>>>(PF, W3c, b3, nullptr,
        (void*)P3, NTOKH, 512, 512);

    // 8. modulation + channel softmax: half-plane in -> FULL plane out (mirror writes)
    mod_kernel<<<4224, blk, 0, stream>>>(X1, P3, alpha, A2);
    // 9. complex GEMM w2 + softshrink (full plane) -> O2b bf16
    gemm_mfma_kernel<4, 64><<<1024, blk, 0, stream>>>(A2, W2c, b2, nullptr,
        (void*)O2b, NTOK, 512, 512);

    // 10-11. inverse FFT2: H-axis then W-axis (real out, fused +RES; final stage keeps lo)
    dftm_kernel<1, 0, 4, 0><<<1024, blk, 0, stream>>>(O2b, TW_I, M2, nullptr,
        2, 2097152L, 512L, 128L, 32768L, 256L, 2097152L, 256L, 128L, 32768L, 16384L, 63);
    dftm_kernel<1, 1, 4, 1><<<1024, blk, 0, stream>>>(M2, TW_I, Hb, RES,
        2, 2097152L, 32768L, 128L, 256L, 16384L, 1048576L, 16384L, 128L, 256L, 0L, 63);

    // 12. LN2 -> bf16
    ln2_kernel<<<32768, blk, 0, stream>>>(Hb, g2, be2, Mb16);
    // 13. MLP fc1 (MFMA) + fast gelu -> fp8 hidden
    gemm_mfma_kernel<6, 64><<<4096, blk, 0, stream>>>(Mb16, WB1, fc1b, nullptr,
        (void*)HIDF8, NTOK, MLPH, HID);
    // 14. MLP fc2 (fp8 MFMA) + bias + h, transposed out
    mlp2_fp8_kernel<<<512, blk, 0, stream>>>(HIDF8, (const u8*)WB2F, fc2b, Hb, out);
}